// Round 6
// baseline (173.785 us; speedup 1.0000x reference)
//
#include <hip/hip_runtime.h>
#include <hip/hip_bf16.h>

// ---------------------------------------------------------------------------
// R13 = R12 + single-wave phase waits + transposed FFN:
//   - Workgroup = ONE wave: __syncthreads() replaced by inline-asm
//     `s_waitcnt lgkmcnt(0)` (+memory clobber). Correct for 1-wave wgs
//     (lockstep + lgkm retirement = LDS visibility); removes the 8 implicit
//     vmcnt(0) drains that serialized global loads at every phase boundary.
//   - Residual x loads issued at kernel top; drain naturally at use.
//   - FFN computed TRANSPOSED (U^T = W1^T h2^T, out^T = W2^T U^T): A- and
//     B-fragments share (lane,word) layout, so prep's W1/W2 fragments serve
//     directly as A-operands; ff-pairing becomes in-lane (no shfl storm) and
//     FFN2 output lands directly in the store layout (sF round-trip gone).
// One wave (64 threads) per token-block of 64 tokens x 16 channels.
// v_mfma_f32_16x16x32_bf16 layouts (m89/m91-verified):
//   C/D: D[m=quad*4+reg][n=lane&15]
//   A:   A[m=lane&15][k=quad*8+j]   (word p = elements 2p(lo16), 2p+1(hi16))
//   B:   B[k=quad*8+j][n=lane&15]
// ---------------------------------------------------------------------------

typedef __attribute__((ext_vector_type(8))) short bf8;   // 8 bf16 (4 VGPRs)
typedef __attribute__((ext_vector_type(4))) float f4;    // 4 fp32 (C/D frag)

union FragU { uint4 u4; uint u[4]; bf8 b; };
union F4U  { uint4 u4; float4 f; };

// single-wave phase boundary: LDS visibility only (no vmcnt drain, no barrier)
#define LWAIT() asm volatile("s_waitcnt lgkmcnt(0)" ::: "memory")

__device__ __forceinline__ uint packbf(float lo, float hi) {   // lo -> bits[15:0]
    union { __hip_bfloat162 h; uint u; } c;
    c.h = __float22bfloat162_rn(make_float2(lo, hi));
    return c.u;
}

// tanh-form gelu: u * sigma(2*sqrt(2/pi)*(u + 0.044715 u^3)), exp2 domain.
__device__ __forceinline__ float gelu_fast(float u) {
    float u2 = u * u;
    float t  = u * (-2.3022079f + -0.1029431f * u2);   // -2*log2e*c1*(1+c2 u^2)
    float e  = __builtin_amdgcn_exp2f(t);
    return u * __builtin_amdgcn_rcpf(1.f + e);
}

#define MFMA(a, b, c) __builtin_amdgcn_mfma_f32_16x16x32_bf16(a, b, c, 0, 0, 0)

// LDS arena (word units), 2304 words = 9216 B. Regions (words):
//  Phase A out: sQ bf16-pairs [64][12] @0, sK [64][12] @768, sV [16][36] @1536
//  Phase P:     sP bf16 [64 queries][36] @0 (V already in regs)
//  Phase LN2:   sH2 [64][12] @0          (over dead sP head)
//  Phase FFN1:  sU bf16-pairs [64][20] @768 (over dead sP mid; B-frag-ready)
#define OQ  0
#define OK  768
#define OV  1536
#define OP  0
#define OH2 0
#define OU  768
#define ARENA 2304

// ws blob layout: per-lane 16 uint4 slots (256 B/lane, 16 KB total):
//  0..5: fWq fWk fWv fW1a fW1b fW2   (packed bf16 fragments; A/B layout-shared)
//  6,7:  ln1g[kb..+3], ln1g[kb+4..+7]   (fp32; zeros for quads 2,3)
//  8,9:  ln1b[kb..+3], ln1b[kb+4..+7]
//  10,11: ln2g[quad4..+3], ln2b[quad4..+3]
//  12:   b1[quad4..+3]   13: b1[16+quad4..+3]   14: b2[quad4..+3]
#define WS_SLOTS 16

// bf16 fragment: value W[k=kb+2p(+1)][n] packed per word; layout serves as
// B[k][n] OR A[m=n][k] (identical lane/word mapping).
__device__ __forceinline__ void loadWfrag(const float* __restrict__ W, int ld,
                                          int n, int kb, bool valid, float scale,
                                          bf8& hf) {
    FragU H;
    if (valid) {
        #pragma unroll
        for (int p = 0; p < 4; ++p)
            H.u[p] = packbf(W[(kb+2*p)*ld+n]*scale, W[(kb+2*p+1)*ld+n]*scale);
    } else {
        H.u4 = make_uint4(0u,0u,0u,0u);
    }
    hf = H.b;
}

__global__ __launch_bounds__(64, 1)
void prep_kernel(const float* __restrict__ Wk, const float* __restrict__ Wq,
                 const float* __restrict__ Wv,
                 const float* __restrict__ ln1g, const float* __restrict__ ln1b,
                 const float* __restrict__ ln2g, const float* __restrict__ ln2b,
                 const float* __restrict__ W1, const float* __restrict__ b1,
                 const float* __restrict__ W2, const float* __restrict__ b2,
                 uint4* __restrict__ ws)
{
    const int lane = threadIdx.x;
    const int c15  = lane & 15;
    const int quad = lane >> 4;
    const int quad4 = quad << 2;
    const bool kv = (quad < 2);
    const int  kb = quad * 8;
    uint4* o = ws + lane * WS_SLOTS;
    FragU t; bf8 f;
    loadWfrag(Wq, 16, c15, kb, kv, 0.25f*1.44269504f, f); t.b = f; o[0] = t.u4;
    loadWfrag(Wk, 16, c15, kb, kv, 1.0f, f);              t.b = f; o[1] = t.u4;
    loadWfrag(Wv, 16, c15, kb, kv, 1.0f, f);              t.b = f; o[2] = t.u4;
    loadWfrag(W1, 32, c15,      kb, kv,   1.0f, f);       t.b = f; o[3] = t.u4;
    loadWfrag(W1, 32, c15 + 16, kb, kv,   1.0f, f);       t.b = f; o[4] = t.u4;
    loadWfrag(W2, 16, c15,      kb, true, 1.0f, f);       t.b = f; o[5] = t.u4;
    F4U z; z.f = make_float4(0.f, 0.f, 0.f, 0.f);
    F4U a, b;
    if (kv) {
        a.f = *(const float4*)(ln1g + kb); b.f = *(const float4*)(ln1g + kb + 4);
    } else { a = z; b = z; }
    o[6] = a.u4; o[7] = b.u4;
    if (kv) {
        a.f = *(const float4*)(ln1b + kb); b.f = *(const float4*)(ln1b + kb + 4);
    } else { a = z; b = z; }
    o[8] = a.u4; o[9] = b.u4;
    a.f = *(const float4*)(ln2g + quad4); o[10] = a.u4;
    a.f = *(const float4*)(ln2b + quad4); o[11] = a.u4;
    a.f = *(const float4*)(b1 + quad4);      o[12] = a.u4;
    a.f = *(const float4*)(b1 + 16 + quad4); o[13] = a.u4;
    a.f = *(const float4*)(b2 + quad4);      o[14] = a.u4;
}

__global__ __launch_bounds__(64, 4)
void tb_kernel(const float* __restrict__ x,
               const uint4* __restrict__ ws,
               float* __restrict__ out)
{
    __shared__ __align__(16) uint lds[ARENA];
    const int lane = threadIdx.x;
    const int c15  = lane & 15;
    const int quad = lane >> 4;
    const int quad4 = quad << 2;
    const size_t base = (size_t)blockIdx.x * (64 * 16);
    const f4 z4 = {0.f, 0.f, 0.f, 0.f};
    const bool kv = (quad < 2);          // K=16 mats: only quads 0,1 carry data
    const int  kb = quad * 8;
    const bool wrE = ((c15 & 1) == 0);

    // ---- early-issue: residual x loads (drain at use; no barriers in the way)
    float4 xr[4];
    #pragma unroll
    for (int qt = 0; qt < 4; ++qt)
        xr[qt] = *(const float4*)(x + base + (size_t)(qt*16 + c15)*16 + quad4);

    // ---- prologue: 15 b128 loads from the pre-packed blob (L2-hot)
    const uint4* wv = ws + lane * WS_SLOTS;
    FragU t;
    t.u4 = wv[0]; const bf8 fWq  = t.b;
    t.u4 = wv[1]; const bf8 fWk  = t.b;
    t.u4 = wv[2]; const bf8 fWv  = t.b;
    t.u4 = wv[3]; const bf8 fW1a = t.b;   // as A: A[m=ff(c15)][k=ch]
    t.u4 = wv[4]; const bf8 fW1b = t.b;   // as A: A[m=ff(16+c15)][k=ch]
    t.u4 = wv[5]; const bf8 fW2f = t.b;   // as A: A[m=c(c15)][k=ff], K=32 full
    F4U fu;
    fu.u4 = wv[6];  const float4 g1a = fu.f;
    fu.u4 = wv[7];  const float4 g1b = fu.f;
    fu.u4 = wv[8];  const float4 b1a = fu.f;
    fu.u4 = wv[9];  const float4 b1b = fu.f;
    fu.u4 = wv[10]; const float4 g2  = fu.f;
    fu.u4 = wv[11]; const float4 b2v = fu.f;
    fu.u4 = wv[12]; const f4 cb0 = {fu.f.x, fu.f.y, fu.f.z, fu.f.w};  // b1[ff 0-15]
    fu.u4 = wv[13]; const f4 cb1 = {fu.f.x, fu.f.y, fu.f.z, fu.f.w};  // b1[ff 16-31]
    fu.u4 = wv[14]; const f4 cb2 = {fu.f.x, fu.f.y, fu.f.z, fu.f.w};  // b2[c]

    // ---- LN1 (fp32, TWO-PASS variance) -> bf16 A-fragments
    bf8 ah[4];
    {
        const float gg[8] = {g1a.x,g1a.y,g1a.z,g1a.w, g1b.x,g1b.y,g1b.z,g1b.w};
        const float bb[8] = {b1a.x,b1a.y,b1a.z,b1a.w, b1b.x,b1b.y,b1b.z,b1b.w};
        #pragma unroll
        for (int mt = 0; mt < 4; ++mt) {
            FragU Ah;
            if (kv) {
                const float4* xp = (const float4*)(x + base + (size_t)(mt*16 + c15)*16 + kb);
                float4 v0 = xp[0], v1 = xp[1];
                float xv[8] = {v0.x,v0.y,v0.z,v0.w, v1.x,v1.y,v1.z,v1.w};
                float s = 0.f;
                #pragma unroll
                for (int j = 0; j < 8; ++j) s += xv[j];
                s  += __shfl_xor(s, 16);    // combine half-rows (quads 0,1)
                float mu = s * 0.0625f;
                float s2 = 0.f;
                #pragma unroll
                for (int j = 0; j < 8; ++j) { float d = xv[j] - mu; s2 += d*d; }
                s2 += __shfl_xor(s2, 16);   // two-pass variance
                float var  = s2 * 0.0625f;
                float rstd = rsqrtf(var + 1e-5f);
                float h[8];
                #pragma unroll
                for (int j = 0; j < 8; ++j) h[j] = (xv[j]-mu)*rstd*gg[j] + bb[j];
                #pragma unroll
                for (int p = 0; p < 4; ++p) Ah.u[p] = packbf(h[2*p], h[2*p+1]);
            } else {
                Ah.u4 = make_uint4(0u,0u,0u,0u);
            }
            ah[mt] = Ah.b;
        }
    }

    // ---- projections -> packed bf16 LDS tiles
    //  sQ/sK: [tok][chpair] stride 12; sV: [ch][tokpair] stride 36
    #pragma unroll
    for (int mt = 0; mt < 4; ++mt) {
        f4 qc = MFMA(ah[mt], fWq, z4);
        f4 kc = MFMA(ah[mt], fWk, z4);
        f4 vc = MFMA(ah[mt], fWv, z4);
        #pragma unroll
        for (int r = 0; r < 4; ++r) {
            const int tok = mt*16 + quad4 + r;
            float qo = __shfl_xor(qc[r], 1);
            float ko = __shfl_xor(kc[r], 1);
            if (wrE) {
                lds[OQ + tok*12 + (c15>>1)] = packbf(qc[r], qo);
                lds[OK + tok*12 + (c15>>1)] = packbf(kc[r], ko);
            }
        }
        *(uint2*)(lds + OV + c15*36 + mt*8 + quad*2) =
            make_uint2(packbf(vc[0], vc[1]), packbf(vc[2], vc[3]));
    }
    LWAIT();   // B1: packed Q/K/V visible (single-wave: lgkm retire suffices)

    // ---- S^T = K.Q^T, causal triangle only (10 MFMAs); scores in log2 units
    bf8 qb[4];                     // B-frags: B[k=ch][n=query] per query-tile
    #pragma unroll
    for (int qt = 0; qt < 4; ++qt) {
        FragU H;
        if (kv) H.u4 = *(const uint4*)(lds + OQ + (qt*16 + c15)*12 + quad4);
        else    H.u4 = make_uint4(0u,0u,0u,0u);
        qb[qt] = H.b;
    }
    f4 st[4][4];                   // st[kt][qt]: S^T[key=kt*16+quad4+r][query=qt*16+c15]
    #pragma unroll
    for (int kt = 0; kt < 4; ++kt) {
        FragU H;                   // A-frag: A[m=key][k=ch]
        if (kv) H.u4 = *(const uint4*)(lds + OK + (kt*16 + c15)*12 + quad4);
        else    H.u4 = make_uint4(0u,0u,0u,0u);
        bf8 ka = H.b;
        #pragma unroll
        for (int qt = 3; qt >= 0; --qt)
            if (qt >= kt)          // compile-time (unrolled): triangle only
                st[kt][qt] = MFMA(ka, qb[qt], z4);
    }
    // causal mask on diagonal tiles
    #pragma unroll
    for (int qt = 0; qt < 4; ++qt)
        #pragma unroll
        for (int r = 0; r < 4; ++r)
            st[qt][qt][r] = (quad4 + r <= c15) ? st[qt][qt][r] : -1e30f;

    // ---- direct softmax per query column (native exp2; scores in log2 units)
    float linv[4];
    #pragma unroll
    for (int qt = 0; qt < 4; ++qt) {
        float mx = fmaxf(fmaxf(st[0][qt][0], st[0][qt][1]),
                         fmaxf(st[0][qt][2], st[0][qt][3]));
        #pragma unroll
        for (int kt = 1; kt < 4; ++kt) {
            if (kt <= qt) {
                float mk = fmaxf(fmaxf(st[kt][qt][0], st[kt][qt][1]),
                                 fmaxf(st[kt][qt][2], st[kt][qt][3]));
                mx = fmaxf(mx, mk);
            }
        }
        mx = fmaxf(mx, __shfl_xor(mx, 16));
        mx = fmaxf(mx, __shfl_xor(mx, 32));
        float l = 0.f;
        #pragma unroll
        for (int kt = 0; kt < 4; ++kt) {
            if (kt <= qt) {
                #pragma unroll
                for (int r = 0; r < 4; ++r) {
                    float p = __builtin_amdgcn_exp2f(st[kt][qt][r] - mx);
                    st[kt][qt][r] = p;
                    l += p;
                }
            }
        }
        l += __shfl_xor(l, 16);
        l += __shfl_xor(l, 32);
        linv[qt] = __builtin_amdgcn_rcpf(l);   // l in [1,64], well-conditioned
    }

    // ---- V A-fragments into registers BEFORE sP overwrites the arena
    bf8 va[2];                     // A[m=ch][k=key]
    #pragma unroll
    for (int kc = 0; kc < 2; ++kc) {
        FragU H;
        H.u4 = *(const uint4*)(lds + OV + c15*36 + kc*16 + quad4);
        va[kc] = H.b;
    }
    LWAIT();   // B2a: V reads retired (WAR vs sP writes below)

    // ---- pack P (bf16, unnormalized, in-lane key-pairs) -> sP [query][36]
    #pragma unroll
    for (int qt = 0; qt < 4; ++qt) {
        const int rowo = OP + (qt*16 + c15)*36 + quad*2;
        #pragma unroll
        for (int kt = 0; kt < 4; ++kt) {
            uint2 w;
            if (kt <= qt) {
                w.x = packbf(st[kt][qt][0], st[kt][qt][1]);
                w.y = packbf(st[kt][qt][2], st[kt][qt][3]);
            } else w = make_uint2(0u, 0u);
            *(uint2*)(lds + rowo + kt*8) = w;
        }
    }
    LWAIT();   // B2b: sP visible

    // ---- y^T = V^T.P (6 MFMAs)
    f4 yt[4];                      // yt[qt]: y[query=qt*16+c15][ch=quad4+r]
    #pragma unroll
    for (int qt = 0; qt < 4; ++qt) {
        f4 acc = z4;
        #pragma unroll
        for (int kc = 0; kc < 2; ++kc) {
            if (kc == 0 || qt >= 2) {   // keys>=32 only for queries>=32
                FragU P_;
                P_.u4 = *(const uint4*)(lds + OP + (qt*16 + c15)*36 + kc*16 + quad4);
                acc = MFMA(va[kc], P_.b, acc);
            }
        }
        yt[qt] = acc;
    }

    // ---- residual 1 (y layout: query=qt*16+c15, ch=quad4+r)
    float x2v[4][4];
    #pragma unroll
    for (int qt = 0; qt < 4; ++qt) {
        const float li = linv[qt];
        x2v[qt][0] = xr[qt].x + yt[qt][0]*li;
        x2v[qt][1] = xr[qt].y + yt[qt][1]*li;
        x2v[qt][2] = xr[qt].z + yt[qt][2]*li;
        x2v[qt][3] = xr[qt].w + yt[qt][3]*li;
    }
    LWAIT();   // B3: sP reads retired (WAR vs sH2 writes)

    // ---- LN2 (two-pass, cross-quad butterfly) -> packed bf16 h2 [tok][chpair]
    #pragma unroll
    for (int qt = 0; qt < 4; ++qt) {
        float s = x2v[qt][0]+x2v[qt][1]+x2v[qt][2]+x2v[qt][3];
        s += __shfl_xor(s, 16); s += __shfl_xor(s, 32);
        float mu = s * 0.0625f;
        float d0 = x2v[qt][0]-mu, d1 = x2v[qt][1]-mu,
              d2 = x2v[qt][2]-mu, d3 = x2v[qt][3]-mu;
        float s2 = d0*d0 + d1*d1 + d2*d2 + d3*d3;
        s2 += __shfl_xor(s2, 16); s2 += __shfl_xor(s2, 32);
        float rstd = rsqrtf(s2 * 0.0625f + 1e-5f);
        float h0 = d0*rstd*g2.x + b2v.x;
        float h1 = d1*rstd*g2.y + b2v.y;
        float h2_ = d2*rstd*g2.z + b2v.z;
        float h3 = d3*rstd*g2.w + b2v.w;
        *(uint2*)(lds + OH2 + (qt*16 + c15)*12 + quad*2) =
            make_uint2(packbf(h0, h1), packbf(h2_, h3));
    }
    LWAIT();   // B4: sH2 visible

    // ---- FFN1 TRANSPOSED: U^T[ff][tok] = W1^T.h2^T  (8 MFMAs)
    //  A = fW1a/fW1b (prep frag doubles as A); B = h2^T read per token-tile.
    f4 uu[2][4];
    #pragma unroll
    for (int qt = 0; qt < 4; ++qt) {
        FragU H;                   // B[k=ch][n=tok]: row tok, word = ch-pair
        if (kv) H.u4 = *(const uint4*)(lds + OH2 + (qt*16 + c15)*12 + quad4);
        else    H.u4 = make_uint4(0u,0u,0u,0u);
        uu[0][qt] = MFMA(fW1a, H.b, cb0);
        uu[1][qt] = MFMA(fW1b, H.b, cb1);
    }
    // gelu + in-lane ff-pairing -> sU [tok][ffpair] stride 20 (B-frag-ready)
    #pragma unroll
    for (int qt = 0; qt < 4; ++qt) {
        const int row = OU + (qt*16 + c15)*20;
        #pragma unroll
        for (int nt = 0; nt < 2; ++nt) {
            float e0 = gelu_fast(uu[nt][qt][0]);
            float e1 = gelu_fast(uu[nt][qt][1]);
            float e2 = gelu_fast(uu[nt][qt][2]);
            float e3 = gelu_fast(uu[nt][qt][3]);
            *(uint2*)(lds + row + nt*8 + quad*2) =
                make_uint2(packbf(e0, e1), packbf(e2, e3));
        }
    }
    LWAIT();   // B5: sU visible

    // ---- FFN2 TRANSPOSED (native K=32, 4 MFMAs) -> direct store layout
    #pragma unroll
    for (int qt = 0; qt < 4; ++qt) {
        FragU H;                   // B[k=ff][n=tok]
        H.u4 = *(const uint4*)(lds + OU + (qt*16 + c15)*20 + quad4);
        f4 fo = MFMA(fW2f, H.b, cb2);   // D[m=c=quad4+r][n=tok=qt*16+c15]
        float4 o;
        o.x = x2v[qt][0] + fo[0];
        o.y = x2v[qt][1] + fo[1];
        o.z = x2v[qt][2] + fo[2];
        o.w = x2v[qt][3] + fo[3];
        *(float4*)(out + base + (size_t)(qt*16 + c15)*16 + quad4) = o;
    }
}

extern "C" void kernel_launch(void* const* d_in, const int* in_sizes, int n_in,
                              void* d_out, int out_size, void* d_ws, size_t ws_size,
                              hipStream_t stream) {
    const float* x     = (const float*)d_in[0];
    const float* Wk    = (const float*)d_in[1];
    const float* Wq    = (const float*)d_in[2];
    const float* Wv    = (const float*)d_in[3];
    const float* ln1_g = (const float*)d_in[4];
    const float* ln1_b = (const float*)d_in[5];
    const float* ln2_g = (const float*)d_in[6];
    const float* ln2_b = (const float*)d_in[7];
    const float* W1    = (const float*)d_in[8];
    const float* b1    = (const float*)d_in[9];
    const float* W2    = (const float*)d_in[10];
    const float* b2    = (const float*)d_in[11];
    float* out = (float*)d_out;
    uint4* ws = (uint4*)d_ws;

    prep_kernel<<<1, 64, 0, stream>>>(Wk, Wq, Wv, ln1_g, ln1_b, ln2_g, ln2_b,
                                      W1, b1, W2, b2, ws);
    const int n_blocks = in_sizes[0] / (64 * 16);   // 16384
    tb_kernel<<<n_blocks, 64, 0, stream>>>(x, ws, out);
}

// Round 7
// 173.296 us; speedup vs baseline: 1.0028x; 1.0028x over previous
//
#include <hip/hip_runtime.h>
#include <hip/hip_bf16.h>

// ---------------------------------------------------------------------------
// R14 = R13 + 4 independent waves per workgroup:
//   16384 one-wave wgs kept only ~11 waves/CU resident (wg launch/retire
//   machinery can't keep 17 single-wave slots full). Packing 4 fully
//   independent waves (4 consecutive token-blocks, private LDS slices, NO
//   barriers) into one 256-thread wg -> 4 wgs/CU x 4 waves = 16 waves/CU
//   and 4x fewer dispatches. NOT R11's serial grid-stride (which stretched
//   wave lifetime 4x and thrashed L3): here the 4 blocks run in parallel,
//   same footprint/order as 4 old wgs.
// Per-wave program unchanged from R13:
//   - phase waits = inline `s_waitcnt lgkmcnt(0)` (single-wave semantics)
//   - prep kernel pre-packs weight fragments / ln params / biases into d_ws
//   - log2-domain scores -> native exp2; rcp for 1/l; tanh-gelu
//   - transposed FFN (prep frags double as A-operands; no sF round-trip)
// v_mfma_f32_16x16x32_bf16 layouts (m89/m91-verified):
//   C/D: D[m=quad*4+reg][n=lane&15]
//   A:   A[m=lane&15][k=quad*8+j]   (word p = elements 2p(lo16), 2p+1(hi16))
//   B:   B[k=quad*8+j][n=lane&15]
// ---------------------------------------------------------------------------

typedef __attribute__((ext_vector_type(8))) short bf8;   // 8 bf16 (4 VGPRs)
typedef __attribute__((ext_vector_type(4))) float f4;    // 4 fp32 (C/D frag)

union FragU { uint4 u4; uint u[4]; bf8 b; };
union F4U  { uint4 u4; float4 f; };

// intra-wave phase boundary: LDS visibility only (no vmcnt drain, no barrier)
#define LWAIT() asm volatile("s_waitcnt lgkmcnt(0)" ::: "memory")

__device__ __forceinline__ uint packbf(float lo, float hi) {   // lo -> bits[15:0]
    union { __hip_bfloat162 h; uint u; } c;
    c.h = __float22bfloat162_rn(make_float2(lo, hi));
    return c.u;
}

// tanh-form gelu: u * sigma(2*sqrt(2/pi)*(u + 0.044715 u^3)), exp2 domain.
__device__ __forceinline__ float gelu_fast(float u) {
    float u2 = u * u;
    float t  = u * (-2.3022079f + -0.1029431f * u2);   // -2*log2e*c1*(1+c2 u^2)
    float e  = __builtin_amdgcn_exp2f(t);
    return u * __builtin_amdgcn_rcpf(1.f + e);
}

#define MFMA(a, b, c) __builtin_amdgcn_mfma_f32_16x16x32_bf16(a, b, c, 0, 0, 0)

// Per-wave LDS slice (word units), 2304 words = 9216 B. Regions (words):
//  Phase A out: sQ bf16-pairs [64][12] @0, sK [64][12] @768, sV [16][36] @1536
//  Phase P:     sP bf16 [64 queries][36] @0 (V already in regs)
//  Phase LN2:   sH2 [64][12] @0          (over dead sP head)
//  Phase FFN1:  sU bf16-pairs [64][20] @768 (over dead sP mid; B-frag-ready)
#define OQ  0
#define OK  768
#define OV  1536
#define OP  0
#define OH2 0
#define OU  768
#define WARENA 2304
#define NWAVES 4

// ws blob layout: per-lane 16 uint4 slots (256 B/lane, 16 KB total):
//  0..5: fWq fWk fWv fW1a fW1b fW2   (packed bf16 fragments; A/B layout-shared)
//  6,7:  ln1g[kb..+3], ln1g[kb+4..+7]   (fp32; zeros for quads 2,3)
//  8,9:  ln1b[kb..+3], ln1b[kb+4..+7]
//  10,11: ln2g[quad4..+3], ln2b[quad4..+3]
//  12:   b1[quad4..+3]   13: b1[16+quad4..+3]   14: b2[quad4..+3]
#define WS_SLOTS 16

// bf16 fragment: value W[k=kb+2p(+1)][n] packed per word; layout serves as
// B[k][n] OR A[m=n][k] (identical lane/word mapping).
__device__ __forceinline__ void loadWfrag(const float* __restrict__ W, int ld,
                                          int n, int kb, bool valid, float scale,
                                          bf8& hf) {
    FragU H;
    if (valid) {
        #pragma unroll
        for (int p = 0; p < 4; ++p)
            H.u[p] = packbf(W[(kb+2*p)*ld+n]*scale, W[(kb+2*p+1)*ld+n]*scale);
    } else {
        H.u4 = make_uint4(0u,0u,0u,0u);
    }
    hf = H.b;
}

__global__ __launch_bounds__(64, 1)
void prep_kernel(const float* __restrict__ Wk, const float* __restrict__ Wq,
                 const float* __restrict__ Wv,
                 const float* __restrict__ ln1g, const float* __restrict__ ln1b,
                 const float* __restrict__ ln2g, const float* __restrict__ ln2b,
                 const float* __restrict__ W1, const float* __restrict__ b1,
                 const float* __restrict__ W2, const float* __restrict__ b2,
                 uint4* __restrict__ ws)
{
    const int lane = threadIdx.x;
    const int c15  = lane & 15;
    const int quad = lane >> 4;
    const int quad4 = quad << 2;
    const bool kv = (quad < 2);
    const int  kb = quad * 8;
    uint4* o = ws + lane * WS_SLOTS;
    FragU t; bf8 f;
    loadWfrag(Wq, 16, c15, kb, kv, 0.25f*1.44269504f, f); t.b = f; o[0] = t.u4;
    loadWfrag(Wk, 16, c15, kb, kv, 1.0f, f);              t.b = f; o[1] = t.u4;
    loadWfrag(Wv, 16, c15, kb, kv, 1.0f, f);              t.b = f; o[2] = t.u4;
    loadWfrag(W1, 32, c15,      kb, kv,   1.0f, f);       t.b = f; o[3] = t.u4;
    loadWfrag(W1, 32, c15 + 16, kb, kv,   1.0f, f);       t.b = f; o[4] = t.u4;
    loadWfrag(W2, 16, c15,      kb, true, 1.0f, f);       t.b = f; o[5] = t.u4;
    F4U z; z.f = make_float4(0.f, 0.f, 0.f, 0.f);
    F4U a, b;
    if (kv) {
        a.f = *(const float4*)(ln1g + kb); b.f = *(const float4*)(ln1g + kb + 4);
    } else { a = z; b = z; }
    o[6] = a.u4; o[7] = b.u4;
    if (kv) {
        a.f = *(const float4*)(ln1b + kb); b.f = *(const float4*)(ln1b + kb + 4);
    } else { a = z; b = z; }
    o[8] = a.u4; o[9] = b.u4;
    a.f = *(const float4*)(ln2g + quad4); o[10] = a.u4;
    a.f = *(const float4*)(ln2b + quad4); o[11] = a.u4;
    a.f = *(const float4*)(b1 + quad4);      o[12] = a.u4;
    a.f = *(const float4*)(b1 + 16 + quad4); o[13] = a.u4;
    a.f = *(const float4*)(b2 + quad4);      o[14] = a.u4;
}

__global__ __launch_bounds__(64 * NWAVES, 4)
void tb_kernel(const float* __restrict__ x,
               const uint4* __restrict__ ws,
               float* __restrict__ out)
{
    __shared__ __align__(16) uint lds_all[NWAVES * WARENA];
    const int tid  = threadIdx.x;
    const int lane = tid & 63;
    const int wid  = tid >> 6;
    uint* __restrict__ lds = lds_all + wid * WARENA;   // private per-wave slice
    const int c15  = lane & 15;
    const int quad = lane >> 4;
    const int quad4 = quad << 2;
    const size_t base = (size_t)(blockIdx.x * NWAVES + wid) * (64 * 16);
    const f4 z4 = {0.f, 0.f, 0.f, 0.f};
    const bool kv = (quad < 2);          // K=16 mats: only quads 0,1 carry data
    const int  kb = quad * 8;
    const bool wrE = ((c15 & 1) == 0);

    // ---- early-issue: residual x loads (drain at use; no barriers in the way)
    float4 xr[4];
    #pragma unroll
    for (int qt = 0; qt < 4; ++qt)
        xr[qt] = *(const float4*)(x + base + (size_t)(qt*16 + c15)*16 + quad4);

    // ---- prologue: 15 b128 loads from the pre-packed blob (L2-hot)
    const uint4* wv = ws + lane * WS_SLOTS;
    FragU t;
    t.u4 = wv[0]; const bf8 fWq  = t.b;
    t.u4 = wv[1]; const bf8 fWk  = t.b;
    t.u4 = wv[2]; const bf8 fWv  = t.b;
    t.u4 = wv[3]; const bf8 fW1a = t.b;   // as A: A[m=ff(c15)][k=ch]
    t.u4 = wv[4]; const bf8 fW1b = t.b;   // as A: A[m=ff(16+c15)][k=ch]
    t.u4 = wv[5]; const bf8 fW2f = t.b;   // as A: A[m=c(c15)][k=ff], K=32 full
    F4U fu;
    fu.u4 = wv[6];  const float4 g1a = fu.f;
    fu.u4 = wv[7];  const float4 g1b = fu.f;
    fu.u4 = wv[8];  const float4 b1a = fu.f;
    fu.u4 = wv[9];  const float4 b1b = fu.f;
    fu.u4 = wv[10]; const float4 g2  = fu.f;
    fu.u4 = wv[11]; const float4 b2v = fu.f;
    fu.u4 = wv[12]; const f4 cb0 = {fu.f.x, fu.f.y, fu.f.z, fu.f.w};  // b1[ff 0-15]
    fu.u4 = wv[13]; const f4 cb1 = {fu.f.x, fu.f.y, fu.f.z, fu.f.w};  // b1[ff 16-31]
    fu.u4 = wv[14]; const f4 cb2 = {fu.f.x, fu.f.y, fu.f.z, fu.f.w};  // b2[c]

    // ---- LN1 (fp32, TWO-PASS variance) -> bf16 A-fragments
    bf8 ah[4];
    {
        const float gg[8] = {g1a.x,g1a.y,g1a.z,g1a.w, g1b.x,g1b.y,g1b.z,g1b.w};
        const float bb[8] = {b1a.x,b1a.y,b1a.z,b1a.w, b1b.x,b1b.y,b1b.z,b1b.w};
        #pragma unroll
        for (int mt = 0; mt < 4; ++mt) {
            FragU Ah;
            if (kv) {
                const float4* xp = (const float4*)(x + base + (size_t)(mt*16 + c15)*16 + kb);
                float4 v0 = xp[0], v1 = xp[1];
                float xv[8] = {v0.x,v0.y,v0.z,v0.w, v1.x,v1.y,v1.z,v1.w};
                float s = 0.f;
                #pragma unroll
                for (int j = 0; j < 8; ++j) s += xv[j];
                s  += __shfl_xor(s, 16);    // combine half-rows (quads 0,1)
                float mu = s * 0.0625f;
                float s2 = 0.f;
                #pragma unroll
                for (int j = 0; j < 8; ++j) { float d = xv[j] - mu; s2 += d*d; }
                s2 += __shfl_xor(s2, 16);   // two-pass variance
                float var  = s2 * 0.0625f;
                float rstd = rsqrtf(var + 1e-5f);
                float h[8];
                #pragma unroll
                for (int j = 0; j < 8; ++j) h[j] = (xv[j]-mu)*rstd*gg[j] + bb[j];
                #pragma unroll
                for (int p = 0; p < 4; ++p) Ah.u[p] = packbf(h[2*p], h[2*p+1]);
            } else {
                Ah.u4 = make_uint4(0u,0u,0u,0u);
            }
            ah[mt] = Ah.b;
        }
    }

    // ---- projections -> packed bf16 LDS tiles
    //  sQ/sK: [tok][chpair] stride 12; sV: [ch][tokpair] stride 36
    #pragma unroll
    for (int mt = 0; mt < 4; ++mt) {
        f4 qc = MFMA(ah[mt], fWq, z4);
        f4 kc = MFMA(ah[mt], fWk, z4);
        f4 vc = MFMA(ah[mt], fWv, z4);
        #pragma unroll
        for (int r = 0; r < 4; ++r) {
            const int tok = mt*16 + quad4 + r;
            float qo = __shfl_xor(qc[r], 1);
            float ko = __shfl_xor(kc[r], 1);
            if (wrE) {
                lds[OQ + tok*12 + (c15>>1)] = packbf(qc[r], qo);
                lds[OK + tok*12 + (c15>>1)] = packbf(kc[r], ko);
            }
        }
        *(uint2*)(lds + OV + c15*36 + mt*8 + quad*2) =
            make_uint2(packbf(vc[0], vc[1]), packbf(vc[2], vc[3]));
    }
    LWAIT();   // B1: packed Q/K/V visible (intra-wave: lgkm retire suffices)

    // ---- S^T = K.Q^T, causal triangle only (10 MFMAs); scores in log2 units
    bf8 qb[4];                     // B-frags: B[k=ch][n=query] per query-tile
    #pragma unroll
    for (int qt = 0; qt < 4; ++qt) {
        FragU H;
        if (kv) H.u4 = *(const uint4*)(lds + OQ + (qt*16 + c15)*12 + quad4);
        else    H.u4 = make_uint4(0u,0u,0u,0u);
        qb[qt] = H.b;
    }
    f4 st[4][4];                   // st[kt][qt]: S^T[key=kt*16+quad4+r][query=qt*16+c15]
    #pragma unroll
    for (int kt = 0; kt < 4; ++kt) {
        FragU H;                   // A-frag: A[m=key][k=ch]
        if (kv) H.u4 = *(const uint4*)(lds + OK + (kt*16 + c15)*12 + quad4);
        else    H.u4 = make_uint4(0u,0u,0u,0u);
        bf8 ka = H.b;
        #pragma unroll
        for (int qt = 3; qt >= 0; --qt)
            if (qt >= kt)          // compile-time (unrolled): triangle only
                st[kt][qt] = MFMA(ka, qb[qt], z4);
    }
    // causal mask on diagonal tiles
    #pragma unroll
    for (int qt = 0; qt < 4; ++qt)
        #pragma unroll
        for (int r = 0; r < 4; ++r)
            st[qt][qt][r] = (quad4 + r <= c15) ? st[qt][qt][r] : -1e30f;

    // ---- direct softmax per query column (native exp2; scores in log2 units)
    float linv[4];
    #pragma unroll
    for (int qt = 0; qt < 4; ++qt) {
        float mx = fmaxf(fmaxf(st[0][qt][0], st[0][qt][1]),
                         fmaxf(st[0][qt][2], st[0][qt][3]));
        #pragma unroll
        for (int kt = 1; kt < 4; ++kt) {
            if (kt <= qt) {
                float mk = fmaxf(fmaxf(st[kt][qt][0], st[kt][qt][1]),
                                 fmaxf(st[kt][qt][2], st[kt][qt][3]));
                mx = fmaxf(mx, mk);
            }
        }
        mx = fmaxf(mx, __shfl_xor(mx, 16));
        mx = fmaxf(mx, __shfl_xor(mx, 32));
        float l = 0.f;
        #pragma unroll
        for (int kt = 0; kt < 4; ++kt) {
            if (kt <= qt) {
                #pragma unroll
                for (int r = 0; r < 4; ++r) {
                    float p = __builtin_amdgcn_exp2f(st[kt][qt][r] - mx);
                    st[kt][qt][r] = p;
                    l += p;
                }
            }
        }
        l += __shfl_xor(l, 16);
        l += __shfl_xor(l, 32);
        linv[qt] = __builtin_amdgcn_rcpf(l);   // l in [1,64], well-conditioned
    }

    // ---- V A-fragments into registers BEFORE sP overwrites the arena
    bf8 va[2];                     // A[m=ch][k=key]
    #pragma unroll
    for (int kc = 0; kc < 2; ++kc) {
        FragU H;
        H.u4 = *(const uint4*)(lds + OV + c15*36 + kc*16 + quad4);
        va[kc] = H.b;
    }
    LWAIT();   // B2a: V reads retired (WAR vs sP writes below)

    // ---- pack P (bf16, unnormalized, in-lane key-pairs) -> sP [query][36]
    #pragma unroll
    for (int qt = 0; qt < 4; ++qt) {
        const int rowo = OP + (qt*16 + c15)*36 + quad*2;
        #pragma unroll
        for (int kt = 0; kt < 4; ++kt) {
            uint2 w;
            if (kt <= qt) {
                w.x = packbf(st[kt][qt][0], st[kt][qt][1]);
                w.y = packbf(st[kt][qt][2], st[kt][qt][3]);
            } else w = make_uint2(0u, 0u);
            *(uint2*)(lds + rowo + kt*8) = w;
        }
    }
    LWAIT();   // B2b: sP visible

    // ---- y^T = V^T.P (6 MFMAs)
    f4 yt[4];                      // yt[qt]: y[query=qt*16+c15][ch=quad4+r]
    #pragma unroll
    for (int qt = 0; qt < 4; ++qt) {
        f4 acc = z4;
        #pragma unroll
        for (int kc = 0; kc < 2; ++kc) {
            if (kc == 0 || qt >= 2) {   // keys>=32 only for queries>=32
                FragU P_;
                P_.u4 = *(const uint4*)(lds + OP + (qt*16 + c15)*36 + kc*16 + quad4);
                acc = MFMA(va[kc], P_.b, acc);
            }
        }
        yt[qt] = acc;
    }

    // ---- residual 1 (y layout: query=qt*16+c15, ch=quad4+r)
    float x2v[4][4];
    #pragma unroll
    for (int qt = 0; qt < 4; ++qt) {
        const float li = linv[qt];
        x2v[qt][0] = xr[qt].x + yt[qt][0]*li;
        x2v[qt][1] = xr[qt].y + yt[qt][1]*li;
        x2v[qt][2] = xr[qt].z + yt[qt][2]*li;
        x2v[qt][3] = xr[qt].w + yt[qt][3]*li;
    }
    LWAIT();   // B3: sP reads retired (WAR vs sH2 writes)

    // ---- LN2 (two-pass, cross-quad butterfly) -> packed bf16 h2 [tok][chpair]
    #pragma unroll
    for (int qt = 0; qt < 4; ++qt) {
        float s = x2v[qt][0]+x2v[qt][1]+x2v[qt][2]+x2v[qt][3];
        s += __shfl_xor(s, 16); s += __shfl_xor(s, 32);
        float mu = s * 0.0625f;
        float d0 = x2v[qt][0]-mu, d1 = x2v[qt][1]-mu,
              d2 = x2v[qt][2]-mu, d3 = x2v[qt][3]-mu;
        float s2 = d0*d0 + d1*d1 + d2*d2 + d3*d3;
        s2 += __shfl_xor(s2, 16); s2 += __shfl_xor(s2, 32);
        float rstd = rsqrtf(s2 * 0.0625f + 1e-5f);
        float h0 = d0*rstd*g2.x + b2v.x;
        float h1 = d1*rstd*g2.y + b2v.y;
        float h2_ = d2*rstd*g2.z + b2v.z;
        float h3 = d3*rstd*g2.w + b2v.w;
        *(uint2*)(lds + OH2 + (qt*16 + c15)*12 + quad*2) =
            make_uint2(packbf(h0, h1), packbf(h2_, h3));
    }
    LWAIT();   // B4: sH2 visible

    // ---- FFN1 TRANSPOSED: U^T[ff][tok] = W1^T.h2^T  (8 MFMAs)
    //  A = fW1a/fW1b (prep frag doubles as A); B = h2^T read per token-tile.
    f4 uu[2][4];
    #pragma unroll
    for (int qt = 0; qt < 4; ++qt) {
        FragU H;                   // B[k=ch][n=tok]: row tok, word = ch-pair
        if (kv) H.u4 = *(const uint4*)(lds + OH2 + (qt*16 + c15)*12 + quad4);
        else    H.u4 = make_uint4(0u,0u,0u,0u);
        uu[0][qt] = MFMA(fW1a, H.b, cb0);
        uu[1][qt] = MFMA(fW1b, H.b, cb1);
    }
    // gelu + in-lane ff-pairing -> sU [tok][ffpair] stride 20 (B-frag-ready)
    #pragma unroll
    for (int qt = 0; qt < 4; ++qt) {
        const int row = OU + (qt*16 + c15)*20;
        #pragma unroll
        for (int nt = 0; nt < 2; ++nt) {
            float e0 = gelu_fast(uu[nt][qt][0]);
            float e1 = gelu_fast(uu[nt][qt][1]);
            float e2 = gelu_fast(uu[nt][qt][2]);
            float e3 = gelu_fast(uu[nt][qt][3]);
            *(uint2*)(lds + row + nt*8 + quad*2) =
                make_uint2(packbf(e0, e1), packbf(e2, e3));
        }
    }
    LWAIT();   // B5: sU visible

    // ---- FFN2 TRANSPOSED (native K=32, 4 MFMAs) -> direct store layout
    #pragma unroll
    for (int qt = 0; qt < 4; ++qt) {
        FragU H;                   // B[k=ff][n=tok]
        H.u4 = *(const uint4*)(lds + OU + (qt*16 + c15)*20 + quad4);
        f4 fo = MFMA(fW2f, H.b, cb2);   // D[m=c=quad4+r][n=tok=qt*16+c15]
        float4 o;
        o.x = x2v[qt][0] + fo[0];
        o.y = x2v[qt][1] + fo[1];
        o.z = x2v[qt][2] + fo[2];
        o.w = x2v[qt][3] + fo[3];
        *(float4*)(out + base + (size_t)(qt*16 + c15)*16 + quad4) = o;
    }
}

extern "C" void kernel_launch(void* const* d_in, const int* in_sizes, int n_in,
                              void* d_out, int out_size, void* d_ws, size_t ws_size,
                              hipStream_t stream) {
    const float* x     = (const float*)d_in[0];
    const float* Wk    = (const float*)d_in[1];
    const float* Wq    = (const float*)d_in[2];
    const float* Wv    = (const float*)d_in[3];
    const float* ln1_g = (const float*)d_in[4];
    const float* ln1_b = (const float*)d_in[5];
    const float* ln2_g = (const float*)d_in[6];
    const float* ln2_b = (const float*)d_in[7];
    const float* W1    = (const float*)d_in[8];
    const float* b1    = (const float*)d_in[9];
    const float* W2    = (const float*)d_in[10];
    const float* b2    = (const float*)d_in[11];
    float* out = (float*)d_out;
    uint4* ws = (uint4*)d_ws;

    prep_kernel<<<1, 64, 0, stream>>>(Wk, Wq, Wv, ln1_g, ln1_b, ln2_g, ln2_b,
                                      W1, b1, W2, b2, ws);
    const int n_blocks = in_sizes[0] / (64 * 16);       // 16384
    const int nwg = n_blocks / NWAVES;                  // 4096 wgs x 256 thr
    tb_kernel<<<nwg, 64 * NWAVES, 0, stream>>>(x, ws, out);
}

// Round 8
// 152.755 us; speedup vs baseline: 1.1377x; 1.1345x over previous
//
#include <hip/hip_runtime.h>
#include <hip/hip_bf16.h>

// ---------------------------------------------------------------------------
// R15: switch every GEMM to v_mfma_f32_16x16x16bf16_1k (K=16).
// With K=16 the per-lane fragment layout (k=quad*4+j) COMPOSES with the
// C/D layout (m=quad4+r, n=c15) so operand hand-offs become in-lane packs:
//   - V-proj output  == PV A-fragment            -> sV LDS eliminated
//   - softmax P      == PV B-fragment            -> sP LDS eliminated
//   - LN1/LN2 on xr layout -> A/B frags directly -> sH2 LDS + x re-read gone
//   - FFN1 output    == FFN2 B-fragment          -> sU LDS eliminated
// Remaining LDS: only the Q/K transpose (write [tok][chpair], read b64 frags),
// ONE lgkmcnt wait per block. x is read once (xr) and feeds LN1 AND residual.
// Per-wave issue work ~2x lower than R14; LDS round-trip chain 5 -> 1.
// Layouts (16x16x16, m89/m91-lineage):
//   C/D: D[m=quad*4+reg][n=lane&15]
//   A:   A[m=lane&15][k=quad*4+j]   (word p = elems 2p(lo16), 2p+1(hi16))
//   B:   B[k=quad*4+j][n=lane&15]
// ---------------------------------------------------------------------------

typedef __attribute__((ext_vector_type(4))) short bf4;   // 4 bf16 (2 VGPRs)
typedef __attribute__((ext_vector_type(4))) float f4;    // 4 fp32 (C/D frag)

union Frag2 { uint2 u2; uint u[2]; bf4 b; };
union F4U  { uint4 u4; float4 f; };

// intra-wave phase boundary: LDS visibility only (no vmcnt drain, no barrier)
#define LWAIT() asm volatile("s_waitcnt lgkmcnt(0)" ::: "memory")

__device__ __forceinline__ uint packbf(float lo, float hi) {   // lo -> bits[15:0]
    union { __hip_bfloat162 h; uint u; } c;
    c.h = __float22bfloat162_rn(make_float2(lo, hi));
    return c.u;
}

// tanh-form gelu: u * sigma(2*sqrt(2/pi)*(u + 0.044715 u^3)), exp2 domain.
__device__ __forceinline__ float gelu_fast(float u) {
    float u2 = u * u;
    float t  = u * (-2.3022079f + -0.1029431f * u2);   // -2*log2e*c1*(1+c2 u^2)
    float e  = __builtin_amdgcn_exp2f(t);
    return u * __builtin_amdgcn_rcpf(1.f + e);
}

#define MFMA16(a, b, c) __builtin_amdgcn_mfma_f32_16x16x16bf16_1k(a, b, c, 0, 0, 0)

// Per-wave LDS slice (word units): sQ [64 rows][10] @0, sK [64][10] @640.
// Rows = tokens; words 0..7 = bf16 ch-pairs; stride 10 rotates banks.
#define OQ  0
#define OK  640
#define WARENA 1280
#define NWAVES 4

// ws blob: per-lane 16 uint4 slots (256 B/lane, 16 KB):
//  0: {fWq, fWk}  1: {fWv, fW1a}  2: {fW1b, fW2a}  3: {fW2b, -}
//  4: ln1g[q4..+3] 5: ln1b[q4..+3] 6: ln2g[q4..+3] 7: ln2b[q4..+3]
//  8: b1[q4..+3]   9: b1[16+q4..+3] 10: b2[q4..+3]
#define WS_SLOTS 16

// K=16 bf16 fragment (2 words): element k=q*4+2p(+1), column n, row-major W.
// Serves as B[k][n] or A[m=n][k] (identical lane/word mapping).
__device__ __forceinline__ uint2 wfrag16(const float* __restrict__ W, int ld,
                                         int n, int q, float s) {
    uint2 w;
    w.x = packbf(W[(q*4+0)*ld+n]*s, W[(q*4+1)*ld+n]*s);
    w.y = packbf(W[(q*4+2)*ld+n]*s, W[(q*4+3)*ld+n]*s);
    return w;
}

__global__ __launch_bounds__(64, 1)
void prep_kernel(const float* __restrict__ Wk, const float* __restrict__ Wq,
                 const float* __restrict__ Wv,
                 const float* __restrict__ ln1g, const float* __restrict__ ln1b,
                 const float* __restrict__ ln2g, const float* __restrict__ ln2b,
                 const float* __restrict__ W1, const float* __restrict__ b1,
                 const float* __restrict__ W2, const float* __restrict__ b2,
                 uint4* __restrict__ ws)
{
    const int lane = threadIdx.x;
    const int c15  = lane & 15;
    const int quad = lane >> 4;
    const int quad4 = quad << 2;
    uint4* o = ws + lane * WS_SLOTS;
    // Wq folds 1/sqrt(16) and log2(e): scores land in log2 domain.
    uint2 fq  = wfrag16(Wq, 16, c15, quad, 0.25f*1.44269504f);
    uint2 fk  = wfrag16(Wk, 16, c15, quad, 1.0f);
    uint2 fv  = wfrag16(Wv, 16, c15, quad, 1.0f);
    uint2 f1a = wfrag16(W1, 32, c15,      quad, 1.0f);  // A[m=ff(c15)][k=ch]
    uint2 f1b = wfrag16(W1, 32, c15 + 16, quad, 1.0f);  // A[m=ff(16+c15)][k=ch]
    uint2 f2a = wfrag16(W2,        16, c15, quad, 1.0f); // A[m=ch][k=ff 0..15]
    uint2 f2b = wfrag16(W2 + 256,  16, c15, quad, 1.0f); // A[m=ch][k=ff 16..31]
    o[0] = make_uint4(fq.x, fq.y, fk.x, fk.y);
    o[1] = make_uint4(fv.x, fv.y, f1a.x, f1a.y);
    o[2] = make_uint4(f1b.x, f1b.y, f2a.x, f2a.y);
    o[3] = make_uint4(f2b.x, f2b.y, 0u, 0u);
    F4U a;
    a.f = *(const float4*)(ln1g + quad4); o[4]  = a.u4;
    a.f = *(const float4*)(ln1b + quad4); o[5]  = a.u4;
    a.f = *(const float4*)(ln2g + quad4); o[6]  = a.u4;
    a.f = *(const float4*)(ln2b + quad4); o[7]  = a.u4;
    a.f = *(const float4*)(b1 + quad4);      o[8]  = a.u4;
    a.f = *(const float4*)(b1 + 16 + quad4); o[9]  = a.u4;
    a.f = *(const float4*)(b2 + quad4);      o[10] = a.u4;
}

__global__ __launch_bounds__(64 * NWAVES, 4)
void tb_kernel(const float* __restrict__ x,
               const uint4* __restrict__ ws,
               float* __restrict__ out)
{
    __shared__ __align__(16) uint lds_all[NWAVES * WARENA];
    const int tid  = threadIdx.x;
    const int lane = tid & 63;
    const int wid  = tid >> 6;
    uint* __restrict__ lds = lds_all + wid * WARENA;   // private per-wave slice
    const int c15  = lane & 15;
    const int quad = lane >> 4;
    const int quad4 = quad << 2;
    const size_t base = (size_t)(blockIdx.x * NWAVES + wid) * (64 * 16);
    const f4 z4 = {0.f, 0.f, 0.f, 0.f};
    const bool wrE = ((c15 & 1) == 0);

    // ---- x read ONCE: [tok=qt*16+c15][ch=quad4..+3] feeds LN1 AND residual
    float4 xr[4];
    #pragma unroll
    for (int qt = 0; qt < 4; ++qt)
        xr[qt] = *(const float4*)(x + base + (size_t)(qt*16 + c15)*16 + quad4);

    // ---- prologue: 11 b128 loads from the pre-packed blob (L2-hot)
    const uint4* wv = ws + lane * WS_SLOTS;
    uint4 s0 = wv[0], s1 = wv[1], s2 = wv[2], s3 = wv[3];
    Frag2 T;
    T.u[0]=s0.x; T.u[1]=s0.y; const bf4 fWq  = T.b;
    T.u[0]=s0.z; T.u[1]=s0.w; const bf4 fWk  = T.b;
    T.u[0]=s1.x; T.u[1]=s1.y; const bf4 fWv  = T.b;
    T.u[0]=s1.z; T.u[1]=s1.w; const bf4 fW1a = T.b;
    T.u[0]=s2.x; T.u[1]=s2.y; const bf4 fW1b = T.b;
    T.u[0]=s2.z; T.u[1]=s2.w; const bf4 fW2a = T.b;
    T.u[0]=s3.x; T.u[1]=s3.y; const bf4 fW2b = T.b;
    F4U fu;
    fu.u4 = wv[4];  const float4 g1  = fu.f;
    fu.u4 = wv[5];  const float4 b1l = fu.f;
    fu.u4 = wv[6];  const float4 g2  = fu.f;
    fu.u4 = wv[7];  const float4 b2l = fu.f;
    fu.u4 = wv[8];  const f4 cb0 = {fu.f.x, fu.f.y, fu.f.z, fu.f.w};  // b1[ff q4+r]
    fu.u4 = wv[9];  const f4 cb1 = {fu.f.x, fu.f.y, fu.f.z, fu.f.w};  // b1[16+q4+r]
    fu.u4 = wv[10]; const f4 cb2 = {fu.f.x, fu.f.y, fu.f.z, fu.f.w};  // b2[q4+r]

    // ---- LN1 (all 64 lanes, two-pass variance) -> A-frags in-lane
    bf4 ah[4];
    #pragma unroll
    for (int qt = 0; qt < 4; ++qt) {
        float4 v = xr[qt];
        float s = v.x + v.y + v.z + v.w;
        s += __shfl_xor(s, 16); s += __shfl_xor(s, 32);
        float mu = s * 0.0625f;
        float d0 = v.x-mu, d1 = v.y-mu, d2 = v.z-mu, d3 = v.w-mu;
        float s2 = d0*d0 + d1*d1 + d2*d2 + d3*d3;
        s2 += __shfl_xor(s2, 16); s2 += __shfl_xor(s2, 32);
        float rstd = rsqrtf(s2 * 0.0625f + 1e-5f);
        float h0 = d0*rstd*g1.x + b1l.x;
        float h1 = d1*rstd*g1.y + b1l.y;
        float h2 = d2*rstd*g1.z + b1l.z;
        float h3 = d3*rstd*g1.w + b1l.w;
        Frag2 A; A.u[0] = packbf(h0, h1); A.u[1] = packbf(h2, h3);
        ah[qt] = A.b;     // A[m=tok(c15)][k=ch(quad*4+j)] for tile qt
    }

    // ---- projections (12 MFMA16); V stays in registers as PV A-frags;
    //      Q,K transposed to LDS [tok][chpair] via lane^1 pair exchange
    bf4 va[4];
    #pragma unroll
    for (int mt = 0; mt < 4; ++mt) {
        f4 qc = MFMA16(ah[mt], fWq, z4);   // D[m=tok=q4+r][n=ch=c15]
        f4 kc = MFMA16(ah[mt], fWk, z4);
        f4 vc = MFMA16(ah[mt], fWv, z4);
        #pragma unroll
        for (int r = 0; r < 4; ++r) {
            const int tok = mt*16 + quad4 + r;
            float qo = __shfl_xor(qc[r], 1);
            float ko = __shfl_xor(kc[r], 1);
            if (wrE) {
                lds[OQ + tok*10 + (c15>>1)] = packbf(qc[r], qo);
                lds[OK + tok*10 + (c15>>1)] = packbf(kc[r], ko);
            }
        }
        Frag2 V_;                          // A[m=ch(c15)][k=key(quad*4+j)]
        V_.u[0] = packbf(vc[0], vc[1]);
        V_.u[1] = packbf(vc[2], vc[3]);
        va[mt] = V_.b;
    }
    LWAIT();   // the ONLY phase wait: Q/K tiles visible

    // ---- Q/K fragments (8 ds_read_b64)
    bf4 ka[4], qb[4];
    #pragma unroll
    for (int t = 0; t < 4; ++t) {
        Frag2 A_, B_;
        A_.u2 = *(const uint2*)(lds + OK + (t*16 + c15)*10 + quad*2);
        B_.u2 = *(const uint2*)(lds + OQ + (t*16 + c15)*10 + quad*2);
        ka[t] = A_.b;   // A[m=key(c15)][k=ch(quad*4+j)]
        qb[t] = B_.b;   // B[k=ch(quad*4+j)][n=query(c15)]
    }

    // ---- S^T = K.Q^T, causal triangle (10 MFMA16); log2-domain scores
    f4 st[4][4];   // st[kt][qt]: S^T[key=kt*16+quad4+r][query=qt*16+c15]
    #pragma unroll
    for (int kt = 0; kt < 4; ++kt)
        #pragma unroll
        for (int qt = 3; qt >= 0; --qt)
            if (qt >= kt)
                st[kt][qt] = MFMA16(ka[kt], qb[qt], z4);
    #pragma unroll
    for (int qt = 0; qt < 4; ++qt)
        #pragma unroll
        for (int r = 0; r < 4; ++r)
            st[qt][qt][r] = (quad4 + r <= c15) ? st[qt][qt][r] : -1e30f;

    // ---- direct softmax per query column (native exp2)
    float linv[4];
    #pragma unroll
    for (int qt = 0; qt < 4; ++qt) {
        float mx = fmaxf(fmaxf(st[0][qt][0], st[0][qt][1]),
                         fmaxf(st[0][qt][2], st[0][qt][3]));
        #pragma unroll
        for (int kt = 1; kt < 4; ++kt) {
            if (kt <= qt) {
                float mk = fmaxf(fmaxf(st[kt][qt][0], st[kt][qt][1]),
                                 fmaxf(st[kt][qt][2], st[kt][qt][3]));
                mx = fmaxf(mx, mk);
            }
        }
        mx = fmaxf(mx, __shfl_xor(mx, 16));
        mx = fmaxf(mx, __shfl_xor(mx, 32));
        float l = 0.f;
        #pragma unroll
        for (int kt = 0; kt < 4; ++kt) {
            if (kt <= qt) {
                #pragma unroll
                for (int r = 0; r < 4; ++r) {
                    float p = __builtin_amdgcn_exp2f(st[kt][qt][r] - mx);
                    st[kt][qt][r] = p;
                    l += p;
                }
            }
        }
        l += __shfl_xor(l, 16);
        l += __shfl_xor(l, 32);
        linv[qt] = __builtin_amdgcn_rcpf(l);   // l in [1,64]
    }

    // ---- PV entirely in-register: y^T[qt] = sum_kt MFMA16(va[kt], P-frag)
    f4 yt[4];
    #pragma unroll
    for (int qt = 0; qt < 4; ++qt) {
        f4 acc = z4;
        #pragma unroll
        for (int kt = 0; kt < 4; ++kt) {
            if (kt <= qt) {
                Frag2 P_;              // B[k=key(quad*4+j)][n=query(c15)]
                P_.u[0] = packbf(st[kt][qt][0], st[kt][qt][1]);
                P_.u[1] = packbf(st[kt][qt][2], st[kt][qt][3]);
                acc = MFMA16(va[kt], P_.b, acc);
            }
        }
        yt[qt] = acc;                  // D[m=ch=quad4+r][n=query=qt*16+c15]
    }

    // ---- residual 1 + LN2 + FFN (all in-register; no LDS)
    float x2v[4][4];
    f4 uu0[4], uu1[4];
    #pragma unroll
    for (int qt = 0; qt < 4; ++qt) {
        const float li = linv[qt];
        x2v[qt][0] = xr[qt].x + yt[qt][0]*li;
        x2v[qt][1] = xr[qt].y + yt[qt][1]*li;
        x2v[qt][2] = xr[qt].z + yt[qt][2]*li;
        x2v[qt][3] = xr[qt].w + yt[qt][3]*li;
        // LN2 (two-pass, cross-quad butterfly)
        float s = x2v[qt][0]+x2v[qt][1]+x2v[qt][2]+x2v[qt][3];
        s += __shfl_xor(s, 16); s += __shfl_xor(s, 32);
        float mu = s * 0.0625f;
        float d0 = x2v[qt][0]-mu, d1 = x2v[qt][1]-mu,
              d2 = x2v[qt][2]-mu, d3 = x2v[qt][3]-mu;
        float s2 = d0*d0 + d1*d1 + d2*d2 + d3*d3;
        s2 += __shfl_xor(s2, 16); s2 += __shfl_xor(s2, 32);
        float rstd = rsqrtf(s2 * 0.0625f + 1e-5f);
        float h0 = d0*rstd*g2.x + b2l.x;
        float h1 = d1*rstd*g2.y + b2l.y;
        float h2 = d2*rstd*g2.z + b2l.z;
        float h3 = d3*rstd*g2.w + b2l.w;
        Frag2 Hb;                      // B[k=ch(quad*4+j)][n=tok(c15)]
        Hb.u[0] = packbf(h0, h1); Hb.u[1] = packbf(h2, h3);
        // FFN1 transposed: U^T = W1^T.h2^T   D[m=ff=quad4+r][n=tok]
        uu0[qt] = MFMA16(fW1a, Hb.b, cb0);
        uu1[qt] = MFMA16(fW1b, Hb.b, cb1);
    }
    #pragma unroll
    for (int qt = 0; qt < 4; ++qt) {
        Frag2 Pa, Pb;                  // B[k=ff(quad*4+j)][n=tok(c15)]
        Pa.u[0] = packbf(gelu_fast(uu0[qt][0]), gelu_fast(uu0[qt][1]));
        Pa.u[1] = packbf(gelu_fast(uu0[qt][2]), gelu_fast(uu0[qt][3]));
        Pb.u[0] = packbf(gelu_fast(uu1[qt][0]), gelu_fast(uu1[qt][1]));
        Pb.u[1] = packbf(gelu_fast(uu1[qt][2]), gelu_fast(uu1[qt][3]));
        // FFN2 transposed, K=32 as two K=16 chunks -> direct store layout
        f4 fo = MFMA16(fW2a, Pa.b, cb2);
        fo = MFMA16(fW2b, Pb.b, fo);   // D[m=ch=quad4+r][n=tok=qt*16+c15]
        float4 o;
        o.x = x2v[qt][0] + fo[0];
        o.y = x2v[qt][1] + fo[1];
        o.z = x2v[qt][2] + fo[2];
        o.w = x2v[qt][3] + fo[3];
        *(float4*)(out + base + (size_t)(qt*16 + c15)*16 + quad4) = o;
    }
}

extern "C" void kernel_launch(void* const* d_in, const int* in_sizes, int n_in,
                              void* d_out, int out_size, void* d_ws, size_t ws_size,
                              hipStream_t stream) {
    const float* x     = (const float*)d_in[0];
    const float* Wk    = (const float*)d_in[1];
    const float* Wq    = (const float*)d_in[2];
    const float* Wv    = (const float*)d_in[3];
    const float* ln1_g = (const float*)d_in[4];
    const float* ln1_b = (const float*)d_in[5];
    const float* ln2_g = (const float*)d_in[6];
    const float* ln2_b = (const float*)d_in[7];
    const float* W1    = (const float*)d_in[8];
    const float* b1    = (const float*)d_in[9];
    const float* W2    = (const float*)d_in[10];
    const float* b2    = (const float*)d_in[11];
    float* out = (float*)d_out;
    uint4* ws = (uint4*)d_ws;

    prep_kernel<<<1, 64, 0, stream>>>(Wk, Wq, Wv, ln1_g, ln1_b, ln2_g, ln2_b,
                                      W1, b1, W2, b2, ws);
    const int n_blocks = in_sizes[0] / (64 * 16);       // 16384
    const int nwg = n_blocks / NWAVES;                  // 4096 wgs x 256 thr
    tb_kernel<<<nwg, 64 * NWAVES, 0, stream>>>(x, ws, out);
}